// Round 1
// baseline (649.600 us; speedup 1.0000x reference)
//
#include <hip/hip_runtime.h>
#include <stdint.h>

#define Bb 4
#define Nn 2048
#define Dd 128
#define NE 4096          // N*E
#define ROWS 8192        // B*N
#define CAP 128          // max nnz per CSR row (mean ~41, sd ~6.4 -> 13 sigma safe)
#define NSTEPS 5

typedef short bf16x8 __attribute__((ext_vector_type(8)));
typedef float f32x4 __attribute__((ext_vector_type(4)));
typedef unsigned short u16;

__device__ __forceinline__ float bf2f(u16 u){ union{unsigned int i; float f;} x; x.i=(unsigned int)u<<16; return x.f; }
__device__ __forceinline__ u16 f2bf(float f){ union{float f; unsigned int i;} x; x.f=f; unsigned int r = x.i + 0x7fffu + ((x.i>>16)&1u); return (u16)(r>>16); }

// ---------------- prep kernels ----------------

__global__ void k_zero(int* __restrict__ cnt){
  int i = blockIdx.x*blockDim.x + threadIdx.x;
  if (i < 2*ROWS) cnt[i] = 0;
}

// pack weights to bf16, transposed (out-dim major) for MFMA B-operand loads
__global__ void k_pack(const float* __restrict__ W_in, const float* __restrict__ b_in,
                       const float* __restrict__ W_out, const float* __restrict__ b_out,
                       const float* __restrict__ W_r, const float* __restrict__ W_z,
                       const float* __restrict__ W_h,
                       u16* __restrict__ WioT, float* __restrict__ bio,
                       u16* __restrict__ WcT, u16* __restrict__ WhbT)
{
  int i = blockIdx.x*blockDim.x + threadIdx.x;
  if (i < 512*128){                       // WioT[o*128+k] : cols = [in_e0|in_e1|out_e0|out_e1]
    int o = i>>7, k = i&127;
    int g = o>>7, f = o&127, e = g&1;
    const float* W = (g>=2) ? W_out : W_in;
    WioT[i] = f2bf(W[((size_t)e*128 + k)*128 + f]);
  } else if (i < 512*128+512){            // bio[o]
    int o = i - 512*128; int g = o>>7, f = o&127;
    bio[o] = (g>=2 ? b_out : b_in)[(g&1)*128 + f];
  } else if (i < 512*128+512+384*384){    // WcT[o*384+k] : cols = [r|z|h_top(rows>=256 zeroed)]
    int j = i - (512*128+512);
    int o = j/384, k = j%384;
    float v;
    if (o < 128)      v = W_r[(size_t)k*128 + o];
    else if (o < 256) v = W_z[(size_t)k*128 + (o-128)];
    else              v = (k < 256) ? W_h[(size_t)k*128 + (o-256)] : 0.f;
    WcT[j] = f2bf(v);
  } else {                                // WhbT[o*128+k] = W_h[256+k][o]
    int j = i - (512*128+512+384*384);
    int o = j>>7, k = j&127;
    WhbT[j] = f2bf(W_h[(size_t)(256+k)*128 + o]);
  }
}

__global__ void k_init(const float* __restrict__ prop, float* __restrict__ h,
                       u16* __restrict__ a_cat){
  int i = blockIdx.x*blockDim.x + threadIdx.x;
  if (i < ROWS*Dd){
    float v = prop[i];
    h[i] = v;
    int r = i>>7, d = i&127;
    a_cat[(size_t)r*384 + 256 + d] = f2bf(v);
  }
}

// build CSR of A (values are exactly 0.0/1.0). One block per (b,n) row.
__global__ void k_csr(const float* __restrict__ A,
                      int* __restrict__ idx_in, int* __restrict__ idx_out,
                      int* __restrict__ cnt_in, int* __restrict__ cnt_out)
{
  int row = blockIdx.x;
  const float* arow = A + (size_t)row * (2*NE);
  for (int c = threadIdx.x*4; c < 2*NE; c += blockDim.x*4){
    float4 v = *reinterpret_cast<const float4*>(arow + c);
    float vv[4] = {v.x, v.y, v.z, v.w};
#pragma unroll
    for (int j=0;j<4;j++){
      if (vv[j] != 0.f){
        int m = c + j;
        if (m < NE){
          int p = atomicAdd(&cnt_in[row], 1);
          if (p < CAP) idx_in[(size_t)row*CAP + p] = m;
        } else {
          int p = atomicAdd(&cnt_out[row], 1);
          if (p < CAP) idx_out[(size_t)row*CAP + p] = m - NE;
        }
      }
    }
  }
}

// ---------------- MFMA GEMM core (no LDS; weights L2-hot) ----------------
// C[m][n] = sum_k A[m][k]*BT[n][k].  A row-major (lda), BT row-major (ldb=K).
// wave computes 64(M) x 16(N). Layouts per verified m89 mapping.
__device__ __forceinline__ void gemm_core(const u16* __restrict__ A, int lda,
    const u16* __restrict__ BT, int ldb, int K,
    int m0, int n0, int lr, int lk, f32x4 acc[4])
{
  for (int k = 0; k < K; k += 32){
    bf16x8 b = *reinterpret_cast<const bf16x8*>(BT + (size_t)(n0+lr)*ldb + k + lk*8);
#pragma unroll
    for (int mt=0; mt<4; mt++){
      bf16x8 a = *reinterpret_cast<const bf16x8*>(A + (size_t)(m0+mt*16+lr)*lda + k + lk*8);
      acc[mt] = __builtin_amdgcn_mfma_f32_16x16x32_bf16(a, b, acc[mt], 0, 0, 0);
    }
  }
}

// GEMM1: ins/outs = h @ [W_in|W_out] + bias. A = bf16 h (a_cat col 256:384, lda=384).
__global__ void k_gemm_io(const u16* __restrict__ hbf,
                          const u16* __restrict__ WioT, const float* __restrict__ bio,
                          u16* __restrict__ ins, u16* __restrict__ outs)
{
  int wave = threadIdx.x>>6, lane = threadIdx.x&63;
  int lr = lane&15, lk = lane>>4;
  int m0 = blockIdx.x*64;
  int n0 = blockIdx.y*64 + wave*16;
  f32x4 acc[4] = {};
  gemm_core(hbf, 384, WioT, 128, 128, m0, n0, lr, lk, acc);
  int o = n0 + lr;
  int g = o>>7, d = o&127;
  u16* dst = (g>=2) ? outs : ins;
  float bv = bio[o];
#pragma unroll
  for (int mt=0; mt<4; mt++){
#pragma unroll
    for (int i=0;i<4;i++){
      int r = m0 + mt*16 + lk*4 + i;
      int b = r>>11, n = r&2047;
      dst[(((size_t)b<<12) + n*2 + (g&1))*128 + d] = f2bf(acc[mt][i] + bv);
    }
  }
}

// sparse gather: a_in/a_out rows summed in f32 from bf16 ins/outs, stored bf16 into a_cat
__global__ void k_gather(const int* __restrict__ cnt_in, const int* __restrict__ cnt_out,
                         const int* __restrict__ idx_in, const int* __restrict__ idx_out,
                         const u16* __restrict__ ins, const u16* __restrict__ outs,
                         u16* __restrict__ a_cat)
{
  int row = blockIdx.x; int b = row>>11;
  int tid = threadIdx.x; int half = tid>>6; int t = tid&63;
  int cnt = half ? cnt_out[row] : cnt_in[row];
  const int* idx = (half ? idx_out : idx_in) + (size_t)row*CAP;
  const u16* src = (half ? outs : ins) + (((size_t)b<<12))*128 + t*2;
  float a0 = 0.f, a1 = 0.f;
  for (int i=0;i<cnt;i++){
    int m = idx[i];
    unsigned int v = *reinterpret_cast<const unsigned int*>(src + (size_t)m*128);
    a0 += bf2f((u16)(v & 0xffffu));
    a1 += bf2f((u16)(v >> 16));
  }
  size_t o = (size_t)row*384 + half*128 + t*2;
  a_cat[o]   = f2bf(a0);
  a_cat[o+1] = f2bf(a1);
}

// GEMM2: T = a_cat @ [W_r|W_z|W_h_top]; epilogue computes r,z, stores rh(bf16), z(f32), hh_top+b_h(f32)
__global__ void k_gemm_gates(const u16* __restrict__ a_cat, const u16* __restrict__ WcT,
                             const float* __restrict__ b_r, const float* __restrict__ b_z,
                             const float* __restrict__ b_h, const float* __restrict__ h,
                             u16* __restrict__ rh, float* __restrict__ zbuf, float* __restrict__ hh)
{
  int wave = threadIdx.x>>6, lane = threadIdx.x&63;
  int lr = lane&15, lk = lane>>4;
  int m0 = blockIdx.x*64;
  int n0 = blockIdx.y*64 + wave*16;
  f32x4 acc[4] = {};
  gemm_core(a_cat, 384, WcT, 384, 384, m0, n0, lr, lk, acc);
  int o = n0 + lr;
#pragma unroll
  for (int mt=0; mt<4; mt++){
#pragma unroll
    for (int i=0;i<4;i++){
      int r = m0 + mt*16 + lk*4 + i;
      float v = acc[mt][i];
      if (o < 128){
        float rr = 1.f/(1.f + expf(-(v + b_r[o])));
        rh[(size_t)r*128 + o] = f2bf(rr * h[(size_t)r*128 + o]);
      } else if (o < 256){
        int dd = o - 128;
        zbuf[(size_t)r*128 + dd] = 1.f/(1.f + expf(-(v + b_z[dd])));
      } else {
        int dd = o - 256;
        hh[(size_t)r*128 + dd] = v + b_h[dd];
      }
    }
  }
}

// GEMM3: H2 = rh @ W_h_bot; epilogue: h_hat=tanh(hh+H2); h=(1-z)h+z*h_hat; write f32 h + bf16 copy
__global__ void k_gemm_final(const u16* __restrict__ rh, const u16* __restrict__ WhbT,
                             const float* __restrict__ hh, const float* __restrict__ zbuf,
                             float* __restrict__ h, u16* __restrict__ a_cat)
{
  int wave = threadIdx.x>>6, lane = threadIdx.x&63;
  int lr = lane&15, lk = lane>>4;
  int m0 = blockIdx.x*64;
  int n0 = blockIdx.y*64 + wave*16;
  f32x4 acc[4] = {};
  gemm_core(rh, 128, WhbT, 128, 128, m0, n0, lr, lk, acc);
  int col = n0 + lr;
#pragma unroll
  for (int mt=0; mt<4; mt++){
#pragma unroll
    for (int i=0;i<4;i++){
      int r = m0 + mt*16 + lk*4 + i;
      size_t ix = (size_t)r*128 + col;
      float hhat = tanhf(acc[mt][i] + hh[ix]);
      float z = zbuf[ix];
      float hold = h[ix];
      float hnew = hold + z*(hhat - hold);
      h[ix] = hnew;
      a_cat[(size_t)r*384 + 256 + col] = f2bf(hnew);
    }
  }
}

// ---------------- host launch ----------------

extern "C" void kernel_launch(void* const* d_in, const int* in_sizes, int n_in,
                              void* d_out, int out_size, void* d_ws, size_t ws_size,
                              hipStream_t stream)
{
  const float* prop  = (const float*)d_in[0];
  const float* A     = (const float*)d_in[1];
  const float* W_in  = (const float*)d_in[2];
  const float* b_in  = (const float*)d_in[3];
  const float* W_out = (const float*)d_in[4];
  const float* b_out = (const float*)d_in[5];
  const float* W_r   = (const float*)d_in[6];
  const float* b_r   = (const float*)d_in[7];
  const float* W_z   = (const float*)d_in[8];
  const float* b_z   = (const float*)d_in[9];
  const float* W_h   = (const float*)d_in[10];
  const float* b_h   = (const float*)d_in[11];

  char* ws = (char*)d_ws;
  size_t off = 0;
  auto nxt = [&](size_t bytes)->char*{ char* p = ws + off; off += (bytes + 255) & ~(size_t)255; return p; };
  int*   cnt    = (int*)  nxt((size_t)2*ROWS*4);
  int*   idx_in = (int*)  nxt((size_t)ROWS*CAP*4);
  int*   idx_out= (int*)  nxt((size_t)ROWS*CAP*4);
  u16*   ins    = (u16*)  nxt((size_t)Bb*NE*Dd*2);
  u16*   outs   = (u16*)  nxt((size_t)Bb*NE*Dd*2);
  u16*   a_cat  = (u16*)  nxt((size_t)ROWS*384*2);
  u16*   rh     = (u16*)  nxt((size_t)ROWS*Dd*2);
  float* zbuf   = (float*)nxt((size_t)ROWS*Dd*4);
  float* hh     = (float*)nxt((size_t)ROWS*Dd*4);
  float* hf     = (float*)nxt((size_t)ROWS*Dd*4);
  u16*   WioT   = (u16*)  nxt(512*128*2);
  float* bio    = (float*)nxt(512*4);
  u16*   WcT    = (u16*)  nxt(384*384*2);
  u16*   WhbT   = (u16*)  nxt(128*128*2);
  int* cnt_in = cnt, *cnt_out = cnt + ROWS;

  k_zero<<<64, 256, 0, stream>>>(cnt);
  k_pack<<<898, 256, 0, stream>>>(W_in, b_in, W_out, b_out, W_r, W_z, W_h, WioT, bio, WcT, WhbT);
  k_init<<<ROWS*Dd/256, 256, 0, stream>>>(prop, hf, a_cat);
  k_csr<<<ROWS, 256, 0, stream>>>(A, idx_in, idx_out, cnt_in, cnt_out);

  for (int t=0; t<NSTEPS; t++){
    k_gemm_io   <<<dim3(ROWS/64, 8), 256, 0, stream>>>(a_cat + 256, WioT, bio, ins, outs);
    k_gather    <<<ROWS, 128, 0, stream>>>(cnt_in, cnt_out, idx_in, idx_out, ins, outs, a_cat);
    k_gemm_gates<<<dim3(ROWS/64, 6), 256, 0, stream>>>(a_cat, WcT, b_r, b_z, b_h, hf, rh, zbuf, hh);
    k_gemm_final<<<dim3(ROWS/64, 2), 256, 0, stream>>>(rh, WhbT, hh, zbuf, hf, a_cat);
  }

  hipMemcpyAsync(d_out, hf, (size_t)ROWS*Dd*4, hipMemcpyDeviceToDevice, stream);
}

// Round 2
// 624.904 us; speedup vs baseline: 1.0395x; 1.0395x over previous
//
#include <hip/hip_runtime.h>
#include <stdint.h>

#define ROWS 8192        // B*N
#define CAP 64           // per-(dir,expert) list cap: mean 20.5, sd 4.5 -> +9.6 sigma
#define NSTEPS 5

typedef short bf16x8 __attribute__((ext_vector_type(8)));
typedef float f32x4 __attribute__((ext_vector_type(4)));
typedef unsigned short u16;
typedef unsigned int u32;

__device__ __forceinline__ float bf2f(u16 u){ union{u32 i; float f;} x; x.i=(u32)u<<16; return x.f; }
__device__ __forceinline__ u16 f2bf(float f){ union{float f; u32 i;} x; x.f=f; u32 r = x.i + 0x7fffu + ((x.i>>16)&1u); return (u16)(r>>16); }

// ---------------- prep ----------------

__global__ void k_zero(int* __restrict__ cnt){
  int i = blockIdx.x*blockDim.x + threadIdx.x;
  if (i < ROWS*4) cnt[i] = 0;
}

// CSR with 4 lists per row: [in-e0 | in-e1 | out-e0 | out-e1], node index n stored
__global__ void k_csr(const float* __restrict__ A,
                      int* __restrict__ idx4, int* __restrict__ cnt4)
{
  int row = blockIdx.x;
  const float* ar = A + (size_t)row * 8192;
  for (int c = threadIdx.x*4; c < 8192; c += 1024){
    float4 v = *reinterpret_cast<const float4*>(ar + c);
    float vv[4] = {v.x, v.y, v.z, v.w};
#pragma unroll
    for (int j=0;j<4;j++){
      if (vv[j] != 0.f){
        int m = c + j;
        int lst = ((m>>12)<<1) | (m&1);      // dir*2 + e   (m index: n*2+e)
        int n = (m & 4095) >> 1;
        int lid = (row<<2) | lst;
        int p = atomicAdd(&cnt4[lid], 1);
        if (p < CAP) idx4[((size_t)lid<<6) + p] = n;
      }
    }
  }
}

// gate-weight selector: row f in [0,384) of the stacked [r|z|h] weights, col o in [0,384)
__device__ __forceinline__ float wsel(const float* __restrict__ Wr, const float* __restrict__ Wz,
                                      const float* __restrict__ Wh, int f, int o){
  if (o < 128) return Wr[(size_t)f*128 + o];
  if (o < 256) return Wz[(size_t)f*128 + (o-128)];
  return (f < 256) ? Wh[(size_t)f*128 + (o-256)] : 0.f;   // h-slot of joined is r*h -> handled by final GEMM
}

// fold: WfT[o][k] (384x640 bf16), bv[4][384] f32 bias-folds, WhbT (128x128 bf16)
__global__ void k_fold(const float* __restrict__ W_in, const float* __restrict__ b_in,
                       const float* __restrict__ W_out, const float* __restrict__ b_out,
                       const float* __restrict__ W_r, const float* __restrict__ W_z,
                       const float* __restrict__ W_h,
                       u16* __restrict__ WfT, float* __restrict__ bv, u16* __restrict__ WhbT)
{
  int i = blockIdx.x*blockDim.x + threadIdx.x;
  if (i < 384*640){
    int o = i / 640, k = i - o*640;
    float s;
    if (k >= 512){
      s = wsel(W_r, W_z, W_h, 256 + (k-512), o);          // direct h part
    } else {
      const float* Wrow; int fb;
      if (k < 256){ Wrow = W_in  + (size_t)((k>>7)&1)*16384 + (size_t)(k&127)*128; fb = 0; }
      else { int kk = k-256; Wrow = W_out + (size_t)(kk>>7)*16384 + (size_t)(kk&127)*128; fb = 128; }
      s = 0.f;
#pragma unroll 8
      for (int f=0; f<128; f++) s += Wrow[f] * wsel(W_r, W_z, W_h, fb+f, o);
    }
    WfT[(size_t)o*640 + k] = f2bf(s);
  } else if (i < 384*640 + 4*384){
    int j = i - 384*640; int q = j / 384, o = j - q*384;
    const float* bp = (q < 2) ? (b_in + q*128) : (b_out + (q-2)*128);
    int fb = (q < 2) ? 0 : 128;
    float s = 0.f;
#pragma unroll 8
    for (int f=0; f<128; f++) s += bp[f] * wsel(W_r, W_z, W_h, fb+f, o);
    bv[j] = s;
  } else if (i < 384*640 + 4*384 + 128*128){
    int j = i - (384*640 + 4*384); int o = j>>7, kk = j&127;
    WhbT[(size_t)o*128 + kk] = f2bf(W_h[(size_t)(256+kk)*128 + o]);
  }
}

__global__ void k_init(const float* __restrict__ prop, float* __restrict__ hf, u16* __restrict__ hbf){
  int i = blockIdx.x*blockDim.x + threadIdx.x;
  if (i < ROWS*128){ float v = prop[i]; hf[i] = v; hbf[i] = f2bf(v); }
}

// ---------------- per-step kernels ----------------

// gather: X[row] = [G_in0 | G_in1 | G_out0 | G_out1] (each 128, bf16), summed in f32 from L2-hot hbf
__global__ void k_gather(const int* __restrict__ cnt4, const int* __restrict__ idx4,
                         const u16* __restrict__ hbf, u16* __restrict__ X)
{
  int row = blockIdx.x; int w = threadIdx.x>>6; int t = threadIdx.x&63;
  int lid = (row<<2) | w;
  int cnt = cnt4[lid]; if (cnt > CAP) cnt = CAP;
  const int* idx = idx4 + ((size_t)lid<<6);
  const u16* hb = hbf + ((size_t)(row>>11) << 11)*128 + (t<<1);
  float a0 = 0.f, a1 = 0.f;
  for (int i=0;i<cnt;i++){
    u32 v = *reinterpret_cast<const u32*>(hb + ((size_t)idx[i]<<7));
    a0 += bf2f((u16)(v & 0xffffu));
    a1 += bf2f((u16)(v >> 16));
  }
  u32 o = ((u32)f2bf(a1)<<16) | (u32)f2bf(a0);
  *reinterpret_cast<u32*>(X + (size_t)row*512 + (w<<7) + (t<<1)) = o;
}

// gates: pre = [X | hbf](8192x640) @ WfT^T + biases; epilogue r/z/hh per column group.
// wave tile 64(m) x 32(n); block 4 waves n-stacked -> 64x128; grid (128, 3)
__global__ __launch_bounds__(256) void k_gates(const u16* __restrict__ X, const u16* __restrict__ hbf,
    const u16* __restrict__ WfT, const float* __restrict__ bv, const int* __restrict__ cnt4,
    const float* __restrict__ b_r, const float* __restrict__ b_z, const float* __restrict__ b_h,
    const float* __restrict__ hf,
    u16* __restrict__ rh, float* __restrict__ zbuf, float* __restrict__ hh)
{
  int wave = threadIdx.x>>6, lane = threadIdx.x&63, lr = lane&15, lk = lane>>4;
  int m0 = blockIdx.x*64, n0 = blockIdx.y*128 + wave*32;
  f32x4 acc[4][2] = {};
  const u16* Ab  = X   + (size_t)(m0+lr)*512 + lk*8;
  const u16* Bb0 = WfT + (size_t)(n0+lr)*640 + lk*8;
  const u16* Bb1 = Bb0 + (size_t)16*640;
#pragma unroll
  for (int k=0;k<512;k+=32){
    bf16x8 b0 = *reinterpret_cast<const bf16x8*>(Bb0+k);
    bf16x8 b1 = *reinterpret_cast<const bf16x8*>(Bb1+k);
#pragma unroll
    for (int mt=0;mt<4;mt++){
      bf16x8 a = *reinterpret_cast<const bf16x8*>(Ab + (size_t)mt*16*512 + k);
      acc[mt][0] = __builtin_amdgcn_mfma_f32_16x16x32_bf16(a, b0, acc[mt][0], 0,0,0);
      acc[mt][1] = __builtin_amdgcn_mfma_f32_16x16x32_bf16(a, b1, acc[mt][1], 0,0,0);
    }
  }
  const u16* A2 = hbf + (size_t)(m0+lr)*128 + lk*8;
#pragma unroll
  for (int k=0;k<128;k+=32){
    bf16x8 b0 = *reinterpret_cast<const bf16x8*>(Bb0+512+k);
    bf16x8 b1 = *reinterpret_cast<const bf16x8*>(Bb1+512+k);
#pragma unroll
    for (int mt=0;mt<4;mt++){
      bf16x8 a = *reinterpret_cast<const bf16x8*>(A2 + (size_t)mt*16*128 + k);
      acc[mt][0] = __builtin_amdgcn_mfma_f32_16x16x32_bf16(a, b0, acc[mt][0], 0,0,0);
      acc[mt][1] = __builtin_amdgcn_mfma_f32_16x16x32_bf16(a, b1, acc[mt][1], 0,0,0);
    }
  }
#pragma unroll
  for (int nt=0;nt<2;nt++){
    int oo = n0 + nt*16 + lr;
    float base = (oo<128) ? b_r[oo] : (oo<256) ? b_z[oo-128] : b_h[oo-256];
    float q0 = bv[oo], q1 = bv[384+oo], q2 = bv[768+oo], q3 = bv[1152+oo];
#pragma unroll
    for (int mt=0;mt<4;mt++){
#pragma unroll
      for (int i=0;i<4;i++){
        int r = m0 + mt*16 + lk*4 + i;
        const int* c = cnt4 + (r<<2);
        float v = acc[mt][nt][i] + base + c[0]*q0 + c[1]*q1 + c[2]*q2 + c[3]*q3;
        if (oo < 128){
          float rr = 1.f/(1.f + expf(-v));
          rh[(size_t)r*128 + oo] = f2bf(rr * hf[(size_t)r*128 + oo]);
        } else if (oo < 256){
          zbuf[(size_t)r*128 + (oo-128)] = 1.f/(1.f + expf(-v));
        } else {
          hh[(size_t)r*128 + (oo-256)] = v;
        }
      }
    }
  }
}

// final: H2 = rh @ W_h_bot; h = (1-z)h + z*tanh(hh+H2); writes hf (f32) + hbf (bf16)
__global__ __launch_bounds__(256) void k_final(const u16* __restrict__ rh, const u16* __restrict__ WhbT,
    const float* __restrict__ hh, const float* __restrict__ zbuf,
    float* __restrict__ hf, u16* __restrict__ hbf)
{
  int wave = threadIdx.x>>6, lane = threadIdx.x&63, lr = lane&15, lk = lane>>4;
  int m0 = blockIdx.x*64, n0 = blockIdx.y*64 + wave*16;
  f32x4 acc[4] = {};
  const u16* Ab = rh   + (size_t)(m0+lr)*128 + lk*8;
  const u16* Bb = WhbT + (size_t)(n0+lr)*128 + lk*8;
#pragma unroll
  for (int k=0;k<128;k+=32){
    bf16x8 b = *reinterpret_cast<const bf16x8*>(Bb+k);
#pragma unroll
    for (int mt=0;mt<4;mt++){
      bf16x8 a = *reinterpret_cast<const bf16x8*>(Ab + (size_t)mt*16*128 + k);
      acc[mt] = __builtin_amdgcn_mfma_f32_16x16x32_bf16(a, b, acc[mt], 0,0,0);
    }
  }
  int col = n0 + lr;
#pragma unroll
  for (int mt=0;mt<4;mt++){
#pragma unroll
    for (int i=0;i<4;i++){
      int r = m0 + mt*16 + lk*4 + i;
      size_t ix = (size_t)r*128 + col;
      float hhat = tanhf(acc[mt][i] + hh[ix]);
      float z = zbuf[ix];
      float ho = hf[ix];
      float hn = ho + z*(hhat - ho);
      hf[ix] = hn;
      hbf[ix] = f2bf(hn);
    }
  }
}

// ---------------- host ----------------

extern "C" void kernel_launch(void* const* d_in, const int* in_sizes, int n_in,
                              void* d_out, int out_size, void* d_ws, size_t ws_size,
                              hipStream_t stream)
{
  const float* prop  = (const float*)d_in[0];
  const float* A     = (const float*)d_in[1];
  const float* W_in  = (const float*)d_in[2];
  const float* b_in  = (const float*)d_in[3];
  const float* W_out = (const float*)d_in[4];
  const float* b_out = (const float*)d_in[5];
  const float* W_r   = (const float*)d_in[6];
  const float* b_r   = (const float*)d_in[7];
  const float* W_z   = (const float*)d_in[8];
  const float* b_z   = (const float*)d_in[9];
  const float* W_h   = (const float*)d_in[10];
  const float* b_h   = (const float*)d_in[11];

  char* ws = (char*)d_ws;
  size_t off = 0;
  auto nxt = [&](size_t bytes)->char*{ char* p = ws + off; off += (bytes + 255) & ~(size_t)255; return p; };
  int*   cnt4  = (int*)  nxt((size_t)ROWS*4*4);
  int*   idx4  = (int*)  nxt((size_t)ROWS*4*CAP*4);
  u16*   X     = (u16*)  nxt((size_t)ROWS*512*2);
  u16*   hbf   = (u16*)  nxt((size_t)ROWS*128*2);
  float* hf    = (float*)nxt((size_t)ROWS*128*4);
  u16*   rh    = (u16*)  nxt((size_t)ROWS*128*2);
  float* zbuf  = (float*)nxt((size_t)ROWS*128*4);
  float* hh    = (float*)nxt((size_t)ROWS*128*4);
  u16*   WfT   = (u16*)  nxt((size_t)384*640*2);
  float* bv    = (float*)nxt((size_t)4*384*4);
  u16*   WhbT  = (u16*)  nxt((size_t)128*128*2);

  k_zero<<<(ROWS*4+255)/256, 256, 0, stream>>>(cnt4);
  k_fold<<<(384*640 + 4*384 + 128*128 + 255)/256, 256, 0, stream>>>(
      W_in, b_in, W_out, b_out, W_r, W_z, W_h, WfT, bv, WhbT);
  k_init<<<(ROWS*128+255)/256, 256, 0, stream>>>(prop, hf, hbf);
  k_csr<<<ROWS, 256, 0, stream>>>(A, idx4, cnt4);

  for (int t=0; t<NSTEPS; t++){
    k_gather<<<ROWS, 256, 0, stream>>>(cnt4, idx4, hbf, X);
    k_gates <<<dim3(ROWS/64, 3), 256, 0, stream>>>(X, hbf, WfT, bv, cnt4,
                                                   b_r, b_z, b_h, hf, rh, zbuf, hh);
    k_final <<<dim3(ROWS/64, 2), 256, 0, stream>>>(rh, WhbT, hh, zbuf, hf, hbf);
  }

  hipMemcpyAsync(d_out, hf, (size_t)ROWS*128*4, hipMemcpyDeviceToDevice, stream);
}

// Round 3
// 406.818 us; speedup vs baseline: 1.5968x; 1.5361x over previous
//
#include <hip/hip_runtime.h>
#include <stdint.h>

#define ROWS 8192        // B*N
#define CAP 64           // per-(dir,expert) list cap: mean 20.5, sd 4.5 -> +9.6 sigma
#define NSTEPS 5

typedef short bf16x8 __attribute__((ext_vector_type(8)));
typedef float f32x4 __attribute__((ext_vector_type(4)));
typedef unsigned short u16;
typedef unsigned int u32;

__device__ __forceinline__ float bf2f(u16 u){ union{u32 i; float f;} x; x.i=(u32)u<<16; return x.f; }
__device__ __forceinline__ u16 f2bf(float f){ union{float f; u32 i;} x; x.f=f; u32 r = x.i + 0x7fffu + ((x.i>>16)&1u); return (u16)(r>>16); }

// rh LDS swizzle: XOR row bits into the 16B-slot bits (G4 fix for stride-256B b128 reads)
#define SW(r, byte) ((byte) ^ ((((r)&7))<<4))

// ---------------- prep ----------------

__device__ __forceinline__ float wsel(const float* __restrict__ Wr, const float* __restrict__ Wz,
                                      const float* __restrict__ Wh, int f, int o){
  if (o < 128) return Wr[(size_t)f*128 + o];
  if (o < 256) return Wz[(size_t)f*128 + (o-128)];
  return (f < 256) ? Wh[(size_t)f*128 + (o-256)] : 0.f;
}

// blocks [0,4096): init hf/hbf from prop. blocks [4096,...): fold weights.
__global__ void k_prep(const float* __restrict__ prop, float* __restrict__ hf, u16* __restrict__ hbf,
                       const float* __restrict__ W_in, const float* __restrict__ b_in,
                       const float* __restrict__ W_out, const float* __restrict__ b_out,
                       const float* __restrict__ W_r, const float* __restrict__ W_z,
                       const float* __restrict__ W_h,
                       u16* __restrict__ WfT, float* __restrict__ bv, u16* __restrict__ WhbT)
{
  int bid = blockIdx.x;
  if (bid < 4096){
    int i = bid*256 + threadIdx.x;        // < ROWS*128
    float v = prop[i]; hf[i] = v; hbf[i] = f2bf(v);
    return;
  }
  int i = (bid-4096)*256 + threadIdx.x;
  if (i < 640*384){                       // WfT[o][k], lanes over o (coalesced reads)
    int k = i/384, o = i - k*384;
    float s;
    if (k >= 512){
      s = wsel(W_r, W_z, W_h, 256 + (k-512), o);
    } else {
      const float* Wrow; int fb;
      if (k < 256){ Wrow = W_in  + (size_t)((k>>7)&1)*16384 + (size_t)(k&127)*128; fb = 0; }
      else { int kk = k-256; Wrow = W_out + (size_t)(kk>>7)*16384 + (size_t)(kk&127)*128; fb = 128; }
      s = 0.f;
#pragma unroll 8
      for (int f=0; f<128; f++) s += Wrow[f] * wsel(W_r, W_z, W_h, fb+f, o);
    }
    WfT[(size_t)o*640 + k] = f2bf(s);
  } else if (i < 640*384 + 4*384){        // bias folds
    int j = i - 640*384; int q = j / 384, o = j - q*384;
    const float* bp = (q < 2) ? (b_in + q*128) : (b_out + (q-2)*128);
    int fb = (q < 2) ? 0 : 128;
    float s = 0.f;
#pragma unroll 8
    for (int f=0; f<128; f++) s += bp[f] * wsel(W_r, W_z, W_h, fb+f, o);
    bv[j] = s;
  } else if (i < 640*384 + 4*384 + 128*128){  // WhbT[o][k] = W_h[256+k][o], lanes over o
    int j = i - (640*384 + 4*384); int kk = j>>7, o = j&127;
    WhbT[(size_t)o*128 + kk] = f2bf(W_h[(size_t)(256+kk)*128 + o]);
  }
}

// CSR via block-local LDS lists (block == row; no global atomics, no zero kernel)
__global__ void k_csr(const float* __restrict__ A,
                      int* __restrict__ idx4, int* __restrict__ cnt4)
{
  __shared__ int scnt[4];
  __shared__ int slist[4][CAP];
  int row = blockIdx.x, tid = threadIdx.x;
  if (tid < 4) scnt[tid] = 0;
  __syncthreads();
  const float* ar = A + (size_t)row * 8192;
  for (int c = tid*4; c < 8192; c += 1024){
    float4 v = *reinterpret_cast<const float4*>(ar + c);
    float vv[4] = {v.x, v.y, v.z, v.w};
#pragma unroll
    for (int j=0;j<4;j++){
      if (vv[j] != 0.f){
        int m = c + j;
        int lst = ((m>>12)<<1) | (m&1);      // dir*2 + e
        int n = (m & 4095) >> 1;
        int p = atomicAdd(&scnt[lst], 1);
        if (p < CAP) slist[lst][p] = n;
      }
    }
  }
  __syncthreads();
  if (tid < 4) cnt4[(row<<2) + tid] = scnt[tid];
  for (int j = tid; j < 4*CAP; j += 256){
    int l = j>>6, p = j&63;
    int c = scnt[l]; if (c > CAP) c = CAP;
    if (p < c) idx4[(((size_t)(row<<2) + l)<<6) + p] = slist[l][p];
  }
}

// ---------------- per-step ----------------

// gather: X[row] = [G_in0|G_in1|G_out0|G_out1]; idx preloaded per-lane, shfl-broadcast
__global__ void k_gather(const int* __restrict__ cnt4, const int* __restrict__ idx4,
                         const u16* __restrict__ hbf, u16* __restrict__ X)
{
  int row = blockIdx.x; int w = threadIdx.x>>6; int t = threadIdx.x&63;
  int lid = (row<<2) | w;
  int cnt = cnt4[lid]; if (cnt > CAP) cnt = CAP;
  const int* idx = idx4 + ((size_t)lid<<6);
  int my = (t < cnt) ? idx[t] : 0;
  const u16* hb = hbf + (((size_t)(row>>11))<<18) + (t<<1);
  float a0 = 0.f, a1 = 0.f;
  for (int i=0;i<cnt;i++){
    int n = __shfl(my, i);
    u32 v = *reinterpret_cast<const u32*>(hb + ((size_t)n<<7));
    a0 += bf2f((u16)(v & 0xffffu));
    a1 += bf2f((u16)(v >> 16));
  }
  u32 o = ((u32)f2bf(a1)<<16) | (u32)f2bf(a0);
  *reinterpret_cast<u32*>(X + (size_t)row*512 + (w<<7) + (t<<1)) = o;
}

// fused gates + final: block owns 32 rows; 8 waves x 48 cols (GEMM1), 8 waves x 16 cols (GEMM2)
__global__ __launch_bounds__(512) void k_step(
    const u16* __restrict__ X, const u16* __restrict__ WfT, const float* __restrict__ bv,
    const int* __restrict__ cnt4,
    const float* __restrict__ b_r, const float* __restrict__ b_z, const float* __restrict__ b_h,
    const u16* __restrict__ WhbT, float* __restrict__ hf, u16* __restrict__ hbf)
{
  __shared__ u16  rh_s[32*128];      // swizzled bf16
  __shared__ float z_s[32][128];
  __shared__ float hh_s[32][128];
  __shared__ int  cnts[32][4];

  int tid = threadIdx.x;
  int wave = tid>>6, lane = tid&63, lr = lane&15, lk = lane>>4;
  int m0 = blockIdx.x*32;

  if (tid < 128) cnts[tid>>2][tid&3] = cnt4[((m0 + (tid>>2))<<2) + (tid&3)];
  __syncthreads();

  // ---- GEMM1: pre[32x384] = [X | hbf] @ WfT^T ----
  int n0 = wave*48;
  f32x4 acc[2][3] = {};
  const u16* Ax = X   + (size_t)(m0+lr)*512 + lk*8;
  const u16* Ah = hbf + (size_t)(m0+lr)*128 + lk*8;
  const u16* Bw = WfT + (size_t)(n0+lr)*640 + lk*8;
#pragma unroll
  for (int k=0;k<512;k+=32){
    bf16x8 b0 = *reinterpret_cast<const bf16x8*>(Bw + k);
    bf16x8 b1 = *reinterpret_cast<const bf16x8*>(Bw + 16*640 + k);
    bf16x8 b2 = *reinterpret_cast<const bf16x8*>(Bw + 32*640 + k);
#pragma unroll
    for (int mt=0;mt<2;mt++){
      bf16x8 a = *reinterpret_cast<const bf16x8*>(Ax + (size_t)mt*16*512 + k);
      acc[mt][0] = __builtin_amdgcn_mfma_f32_16x16x32_bf16(a, b0, acc[mt][0], 0,0,0);
      acc[mt][1] = __builtin_amdgcn_mfma_f32_16x16x32_bf16(a, b1, acc[mt][1], 0,0,0);
      acc[mt][2] = __builtin_amdgcn_mfma_f32_16x16x32_bf16(a, b2, acc[mt][2], 0,0,0);
    }
  }
#pragma unroll
  for (int k=0;k<128;k+=32){
    bf16x8 b0 = *reinterpret_cast<const bf16x8*>(Bw + 512 + k);
    bf16x8 b1 = *reinterpret_cast<const bf16x8*>(Bw + 16*640 + 512 + k);
    bf16x8 b2 = *reinterpret_cast<const bf16x8*>(Bw + 32*640 + 512 + k);
#pragma unroll
    for (int mt=0;mt<2;mt++){
      bf16x8 a = *reinterpret_cast<const bf16x8*>(Ah + (size_t)mt*16*128 + k);
      acc[mt][0] = __builtin_amdgcn_mfma_f32_16x16x32_bf16(a, b0, acc[mt][0], 0,0,0);
      acc[mt][1] = __builtin_amdgcn_mfma_f32_16x16x32_bf16(a, b1, acc[mt][1], 0,0,0);
      acc[mt][2] = __builtin_amdgcn_mfma_f32_16x16x32_bf16(a, b2, acc[mt][2], 0,0,0);
    }
  }

  // ---- epilogue 1: r -> rh (LDS, swizzled), z -> z_s, hh -> hh_s ----
#pragma unroll
  for (int nt=0;nt<3;nt++){
    int oo = n0 + nt*16 + lr;
    float base = (oo<128) ? b_r[oo] : (oo<256) ? b_z[oo-128] : b_h[oo-256];
    float q0 = bv[oo], q1 = bv[384+oo], q2 = bv[768+oo], q3 = bv[1152+oo];
#pragma unroll
    for (int mt=0;mt<2;mt++){
#pragma unroll
      for (int i=0;i<4;i++){
        int rl = mt*16 + lk*4 + i;
        float v = acc[mt][nt][i] + base
                + cnts[rl][0]*q0 + cnts[rl][1]*q1 + cnts[rl][2]*q2 + cnts[rl][3]*q3;
        if (oo < 128){
          float s = 1.f/(1.f + expf(-v));
          float hv = hf[(size_t)(m0+rl)*128 + oo];
          *reinterpret_cast<u16*>(reinterpret_cast<char*>(rh_s) + SW(rl, rl*256 + oo*2)) = f2bf(s*hv);
        } else if (oo < 256){
          z_s[rl][oo-128] = 1.f/(1.f + expf(-v));
        } else {
          hh_s[rl][oo-256] = v;
        }
      }
    }
  }
  __syncthreads();

  // ---- GEMM2: H2[32x128] = rh @ WhbT^T ----
  int c0 = wave*16;
  f32x4 acc2[2] = {};
  const u16* Bh = WhbT + (size_t)(c0+lr)*128 + lk*8;
#pragma unroll
  for (int k=0;k<128;k+=32){
    bf16x8 b = *reinterpret_cast<const bf16x8*>(Bh + k);
#pragma unroll
    for (int mt=0;mt<2;mt++){
      int rr = mt*16 + lr;
      bf16x8 a = *reinterpret_cast<const bf16x8*>(reinterpret_cast<char*>(rh_s) + SW(rr, rr*256 + (k+lk*8)*2));
      acc2[mt] = __builtin_amdgcn_mfma_f32_16x16x32_bf16(a, b, acc2[mt], 0,0,0);
    }
  }

  // ---- epilogue 2: h update ----
#pragma unroll
  for (int mt=0;mt<2;mt++){
#pragma unroll
    for (int i=0;i<4;i++){
      int rl = mt*16 + lk*4 + i;
      int col = c0 + lr;
      size_t ix = (size_t)(m0+rl)*128 + col;
      float hhat = tanhf(acc2[mt][i] + hh_s[rl][col]);
      float zz = z_s[rl][col];
      float ho = hf[ix];
      float hn = ho + zz*(hhat - ho);
      hf[ix] = hn;
      hbf[ix] = f2bf(hn);
    }
  }
}

// ---------------- host ----------------

extern "C" void kernel_launch(void* const* d_in, const int* in_sizes, int n_in,
                              void* d_out, int out_size, void* d_ws, size_t ws_size,
                              hipStream_t stream)
{
  const float* prop  = (const float*)d_in[0];
  const float* A     = (const float*)d_in[1];
  const float* W_in  = (const float*)d_in[2];
  const float* b_in  = (const float*)d_in[3];
  const float* W_out = (const float*)d_in[4];
  const float* b_out = (const float*)d_in[5];
  const float* W_r   = (const float*)d_in[6];
  const float* b_r   = (const float*)d_in[7];
  const float* W_z   = (const float*)d_in[8];
  const float* b_z   = (const float*)d_in[9];
  const float* W_h   = (const float*)d_in[10];
  const float* b_h   = (const float*)d_in[11];

  char* ws = (char*)d_ws;
  size_t off = 0;
  auto nxt = [&](size_t bytes)->char*{ char* p = ws + off; off += (bytes + 255) & ~(size_t)255; return p; };
  int*   cnt4  = (int*)  nxt((size_t)ROWS*4*4);
  int*   idx4  = (int*)  nxt((size_t)ROWS*4*CAP*4);
  u16*   X     = (u16*)  nxt((size_t)ROWS*512*2);
  u16*   hbf   = (u16*)  nxt((size_t)ROWS*128*2);
  float* hf    = (float*)nxt((size_t)ROWS*128*4);
  u16*   WfT   = (u16*)  nxt((size_t)384*640*2);
  float* bv    = (float*)nxt((size_t)4*384*4);
  u16*   WhbT  = (u16*)  nxt((size_t)128*128*2);

  int fold_blocks = (640*384 + 4*384 + 128*128 + 255)/256;
  k_prep<<<4096 + fold_blocks, 256, 0, stream>>>(prop, hf, hbf,
      W_in, b_in, W_out, b_out, W_r, W_z, W_h, WfT, bv, WhbT);
  k_csr<<<ROWS, 256, 0, stream>>>(A, idx4, cnt4);

  for (int t=0; t<NSTEPS; t++){
    k_gather<<<ROWS, 256, 0, stream>>>(cnt4, idx4, hbf, X);
    k_step  <<<ROWS/32, 512, 0, stream>>>(X, WfT, bv, cnt4, b_r, b_z, b_h, WhbT, hf, hbf);
  }

  hipMemcpyAsync(d_out, hf, (size_t)ROWS*128*4, hipMemcpyDeviceToDevice, stream);
}